// Round 3
// baseline (152.116 us; speedup 1.0000x reference)
//
#include <hip/hip_runtime.h>
#include <math.h>

// UpPolyAct: out = c0 + c1*x + 0.25*c2*( z_ee + V + W )
//   R = X M^T, L = M X, OO = L M^T (= (M L^T)^T)
//   z_eo=(R + s sRv^T/64)^2, z_oe=(L + Luv s^T/64)^2, z_oo=OO^2,
//   z_ee=(X + s t^T/64 + u s^T/64 + s s^T sig/4096)^2
//   U = z_oe + z_oo M,  V = M^T U,  W = z_eo M
// MFMA 32x32x16 bf16, transposed-domain chain (verified in R2); tables
// (g circulant, phase-staggered bf16 frag source) precomputed in d_ws by a
// 1-block init kernel (channel-invariant; was rebuilt per block in R2).

typedef short short8 __attribute__((ext_vector_type(8)));
typedef float f32x16 __attribute__((ext_vector_type(16)));

#define LSH 68      // bf16 LDS row stride (rows 8B-aligned, stride 34 dwords)
#define GSTR 132    // staggered g-copy stride (mult of 4 shorts; staggers banks)

__device__ __forceinline__ short f2bf(float f) {
  unsigned u = __float_as_uint(f);
  u += 0x7FFFu + ((u >> 16) & 1u);
  return (short)(u >> 16);
}
__device__ __forceinline__ unsigned pkbf(float a, float b) {
  unsigned ua = __float_as_uint(a); ua += 0x7FFFu + ((ua >> 16) & 1u);
  unsigned ub = __float_as_uint(b); ub += 0x7FFFu + ((ub >> 16) & 1u);
  return (ua >> 16) | (ub & 0xFFFF0000u);
}
__device__ __forceinline__ float bflo(unsigned u) {
  return __uint_as_float(u << 16);
}
__device__ __forceinline__ float bfhi(unsigned u) {
  return __uint_as_float(u & 0xFFFF0000u);
}
__device__ __forceinline__ short8 ldrow(const short* p) {
  union { unsigned u[4]; short8 s; } v;
  const uint2 lo = *(const uint2*)p;
  const uint2 hi = *(const uint2*)(p + 4);
  v.u[0] = lo.x; v.u[1] = lo.y; v.u[2] = hi.x; v.u[3] = hi.y;
  return v.s;
}
// Fragment of M (t=1: "gr" reversed) or M^T-ish (t=0: "g") — content proven
// identical to R2's ftab: value_j = g[ t ? -(basei+j) : (basei+j) & 63 ],
// basei = 16kk + 8q - l31 - 32blk.  gtab[t][p][m] = g[ +/-(m+p) & 63 ].
__device__ __forceinline__ short8 tabfrag(const short* gtab, int t, int blk,
                                          int kk, int q, int l31) {
  const int s = 64 + 16 * kk + 8 * q - l31 - 32 * blk;  // in [1,120]
  const int p = s & 3;
  return ldrow(gtab + (t * 4 + p) * GSTR + (s - p));
}

__global__ void init_tables(float* ws) {
  __shared__ float g64s[64];
  const int tid = threadIdx.x;
  if (tid < 64) {
    const int d = 2 * tid + 1;
    double s = 1.0;
    for (int k = 1; k <= 32; ++k) {
      const int qq = (k * d) & 127;
      s += 2.0 * cos(M_PI * (double)qq / 64.0);
    }
    g64s[tid] = (float)(s / 64.0);
  }
  __syncthreads();
  if (tid < 128) ws[tid] = g64s[tid & 63];  // g2f duplicated f32
  short* gt = (short*)(ws + 128);           // 2 dirs x 4 phases x GSTR shorts
  for (int e = tid; e < 2 * 4 * GSTR; e += 256) {
    const int t = e / (4 * GSTR);
    const int rem = e - t * 4 * GSTR;
    const int p = rem / GSTR;
    const int m = rem - p * GSTR;
    const int li = m + p;
    const int gi = t ? ((-li) & 63) : (li & 63);
    gt[e] = f2bf(g64s[gi]);
  }
}

__global__ __launch_bounds__(256, 5) void uppolyact_kernel(
    const float* __restrict__ x, const float* __restrict__ coef,
    const float* __restrict__ ws, float* __restrict__ out) {
  __shared__ __align__(16) short bufA[64 * LSH];  // Xr -> Zoo
  __shared__ __align__(16) short bufB[64 * LSH];  // Xc -> Zeo
  __shared__ __align__(16) short bufC[64 * LSH];  // Lr -> U^T
  __shared__ __align__(16) unsigned char tabs[2624];  // g2f(512B) + gtab(2112B)
  __shared__ float tp[256];  // t partials, then sRv partials
  __shared__ float up[256];
  __shared__ float tvec[64], uvec[64], svec[64];
  __shared__ float lrp[128];
  __shared__ float sigv;

  const float* g2f = (const float*)tabs;
  const short* gtab = (const short*)(tabs + 512);

  const int tid = threadIdx.x;
  const int lane = tid & 63;
  const int w = tid >> 6;
  const int q = lane >> 5;
  const int l31 = lane & 31;
  const int rb = w >> 1, cb = w & 1;
  const int icol = cb * 32 + l31;  // C-layout column for this lane
  const size_t base = (size_t)blockIdx.x * 4096;

  // ---- P0: load tables from ws; stage X -> Xr (rows) + Xc (cols) bf16 ----
  if (tid < 164) *(float4*)&tabs[16 * tid] = ((const float4*)ws)[tid];
  {
    const float4* xv = (const float4*)(x + base);
#pragma unroll
    for (int e = 0; e < 4; ++e) {
      const int k4 = tid + 256 * e;
      const float4 v = xv[k4];
      const int r = k4 >> 4, c = (k4 & 15) << 2;
      const unsigned d0 = pkbf(v.x, v.y), d1 = pkbf(v.z, v.w);
      *(uint2*)&bufA[r * LSH + c] = make_uint2(d0, d1);
      bufB[(c + 0) * LSH + r] = (short)d0;
      bufB[(c + 1) * LSH + r] = (short)(d0 >> 16);
      bufB[(c + 2) * LSH + r] = (short)d1;
      bufB[(c + 3) * LSH + r] = (short)(d1 >> 16);
    }
  }
  __syncthreads();  // B1

  // ---- P1: Rt = M X^T, Lt = X^T M^T (MFMA); t/u partials; Luv reg-sums ----
  f32x16 Rt, Lt;
#pragma unroll
  for (int r = 0; r < 16; ++r) { Rt[r] = 0.0f; Lt[r] = 0.0f; }
#pragma unroll
  for (int kk = 0; kk < 4; ++kk) {
    const short8 aR = tabfrag(gtab, 1, rb, kk, q, l31);
    const short8 bR = ldrow(&bufA[(cb * 32 + l31) * LSH + kk * 16 + q * 8]);
    Rt = __builtin_amdgcn_mfma_f32_32x32x16_bf16(aR, bR, Rt, 0, 0, 0);
    const short8 aL = ldrow(&bufB[(rb * 32 + l31) * LSH + kk * 16 + q * 8]);
    const short8 bL = tabfrag(gtab, 1, cb, kk, q, l31);
    Lt = __builtin_amdgcn_mfma_f32_32x32x16_bf16(aL, bL, Lt, 0, 0, 0);
  }
  {
    const int jj = tid & 63, pp = tid >> 6;
    float tacc = 0.0f, uacc = 0.0f;
#pragma unroll
    for (int g4 = 0; g4 < 4; ++g4) {
      const uint2 dt = *(const uint2*)&bufB[jj * LSH + 16 * pp + 4 * g4];
      tacc += bflo(dt.x) - bfhi(dt.x) + bflo(dt.y) - bfhi(dt.y);
      const uint2 du = *(const uint2*)&bufA[jj * LSH + 16 * pp + 4 * g4];
      uacc += bflo(du.x) - bfhi(du.x) + bflo(du.y) - bfhi(du.y);
    }
    tp[pp * 64 + jj] = tacc;  // t[j] = sum_i s_i X[i][j], partial over i
    up[pp * 64 + jj] = uacc;  // u[i] = sum_j X[i][j] s_j, partial over j
  }
  {
    float lp = 0.0f;  // Luv[i] = sum_j L[i][j] s_j ; sign = parity(jrow)= r&1
#pragma unroll
    for (int r = 0; r < 16; ++r) lp += (r & 1) ? -Lt[r] : Lt[r];
    lp += __shfl_xor(lp, 32);
    if (q == 0) lrp[rb * 64 + icol] = lp;
  }
  __syncthreads();  // B2

  // ---- P2: write Lr (packed transpose-write); combine tvec/uvec ----
#pragma unroll
  for (int grp = 0; grp < 4; ++grp) {
    const unsigned d0 = pkbf(Lt[4 * grp + 0], Lt[4 * grp + 1]);
    const unsigned d1 = pkbf(Lt[4 * grp + 2], Lt[4 * grp + 3]);
    *(uint2*)&bufC[icol * LSH + 4 * q + 32 * rb + 8 * grp] = make_uint2(d0, d1);
  }
  if (tid < 64) {
    tvec[tid] = tp[tid] + tp[64 + tid] + tp[128 + tid] + tp[192 + tid];
  } else if (tid < 128) {
    const int i = tid - 64;
    uvec[i] = up[i] + up[64 + i] + up[128 + i] + up[192 + i];
  }
  __syncthreads();  // B3

  // ---- P3: OOt = M Lt ; z_oo -> bufA(Zoo) ; sRv matvec partials ; sig ----
  f32x16 OOt;
#pragma unroll
  for (int r = 0; r < 16; ++r) OOt[r] = 0.0f;
#pragma unroll
  for (int kk = 0; kk < 4; ++kk) {
    const short8 a = tabfrag(gtab, 1, rb, kk, q, l31);
    const short8 b = ldrow(&bufC[(cb * 32 + l31) * LSH + kk * 16 + q * 8]);
    OOt = __builtin_amdgcn_mfma_f32_32x32x16_bf16(a, b, OOt, 0, 0, 0);
  }
  {
    const int jj = tid & 63, pp = tid >> 6;
    float sp = 0.0f;  // sRv[j] = sum_m t[m] g[(j-m)&63], partial over m
#pragma unroll
    for (int mm = 0; mm < 16; ++mm) {
      const int m = 16 * pp + mm;
      sp += tvec[m] * g2f[64 + jj - m];
    }
    tp[pp * 64 + jj] = sp;  // reuse tp as sRv partials
  }
  if (tid >= 192) {  // sig = s^T X s = sum_i s_i u[i], wave-3 butterfly
    const int i = tid - 192;
    float v = (i & 1) ? -uvec[i] : uvec[i];
#pragma unroll
    for (int off = 32; off >= 1; off >>= 1) v += __shfl_xor(v, off);
    if (i == 0) sigv = v;
  }
#pragma unroll
  for (int grp = 0; grp < 4; ++grp) {
    const unsigned d0 = pkbf(OOt[4 * grp + 0] * OOt[4 * grp + 0],
                             OOt[4 * grp + 1] * OOt[4 * grp + 1]);
    const unsigned d1 = pkbf(OOt[4 * grp + 2] * OOt[4 * grp + 2],
                             OOt[4 * grp + 3] * OOt[4 * grp + 3]);
    *(uint2*)&bufA[icol * LSH + 4 * q + 32 * rb + 8 * grp] = make_uint2(d0, d1);
  }
  __syncthreads();  // B4

  // ---- P4a: combine svec ----
  if (tid < 64) {
    svec[tid] = tp[tid] + tp[64 + tid] + tp[128 + tid] + tp[192 + tid];
  }
  __syncthreads();  // B5

  // ---- P4b: z_eo -> bufB ; Ut = z_oe + M^T z_oo ; U^T -> bufC ----
  const float sgi = (icol & 1) ? -1.0f : 1.0f;
  const float luv_i = lrp[icol] + lrp[64 + icol];
  f32x16 Ut;
#pragma unroll
  for (int grp = 0; grp < 4; ++grp) {
    const float4 sv = *(const float4*)&svec[4 * q + 32 * rb + 8 * grp];
    float zeo[4];
#pragma unroll
    for (int rr = 0; rr < 4; ++rr) {
      const int r = 4 * grp + rr;
      const float veo = Rt[r] + sgi * (&sv.x)[rr] * (1.0f / 64.0f);
      zeo[rr] = veo * veo;
      const float sgj = (r & 1) ? -1.0f : 1.0f;
      const float voe = Lt[r] + luv_i * sgj * (1.0f / 64.0f);
      Ut[r] = voe * voe;
    }
    *(uint2*)&bufB[icol * LSH + 4 * q + 32 * rb + 8 * grp] =
        make_uint2(pkbf(zeo[0], zeo[1]), pkbf(zeo[2], zeo[3]));
  }
#pragma unroll
  for (int kk = 0; kk < 4; ++kk) {
    const short8 aU = tabfrag(gtab, 0, rb, kk, q, l31);
    const short8 bU = ldrow(&bufA[(cb * 32 + l31) * LSH + kk * 16 + q * 8]);
    Ut = __builtin_amdgcn_mfma_f32_32x32x16_bf16(aU, bU, Ut, 0, 0, 0);
  }
#pragma unroll
  for (int r = 0; r < 16; ++r) {
    const int jrow = (r & 3) + 4 * q + 8 * (r >> 2) + 32 * rb;
    bufC[jrow * LSH + icol] = f2bf(Ut[r]);  // U^T row-major (direct write)
  }
  __syncthreads();  // B6

  // ---- P5: W = z_eo M ; V = M^T U ; epilogue ----
  f32x16 Wv, Vv;
#pragma unroll
  for (int r = 0; r < 16; ++r) { Wv[r] = 0.0f; Vv[r] = 0.0f; }
#pragma unroll
  for (int kk = 0; kk < 4; ++kk) {
    const short8 aW = ldrow(&bufB[(rb * 32 + l31) * LSH + kk * 16 + q * 8]);
    const short8 bW = tabfrag(gtab, 0, cb, kk, q, l31);
    Wv = __builtin_amdgcn_mfma_f32_32x32x16_bf16(aW, bW, Wv, 0, 0, 0);
    const short8 aV = tabfrag(gtab, 0, rb, kk, q, l31);
    const short8 bV = ldrow(&bufC[(cb * 32 + l31) * LSH + kk * 16 + q * 8]);
    Vv = __builtin_amdgcn_mfma_f32_32x32x16_bf16(aV, bV, Vv, 0, 0, 0);
  }

  const float c0 = coef[0], c1 = coef[1];
  const float c2q = 0.25f * coef[2];
  const float* xb = x + base;
  float* ob = out + base;
  const int jcol = icol;
  const float sgjc = (jcol & 1) ? -1.0f : 1.0f;
  const float tj = tvec[jcol];
#pragma unroll
  for (int grp = 0; grp < 4; ++grp) {
    const float4 uv = *(const float4*)&uvec[4 * q + 32 * rb + 8 * grp];
#pragma unroll
    for (int rr = 0; rr < 4; ++rr) {
      const int r = 4 * grp + rr;
      const int irow = (r & 3) + 4 * q + 8 * (r >> 2) + 32 * rb;
      const float sgir = (r & 1) ? -1.0f : 1.0f;
      const float xg = xb[irow * 64 + jcol];
      const float vee = xg + (sgir * tj + (&uv.x)[rr] * sgjc) * (1.0f / 64.0f) +
                        sgir * sgjc * sigv * (1.0f / 4096.0f);
      ob[irow * 64 + jcol] = c0 + c1 * xg + c2q * (vee * vee + Vv[r] + Wv[r]);
    }
  }
}

extern "C" void kernel_launch(void* const* d_in, const int* in_sizes, int n_in,
                              void* d_out, int out_size, void* d_ws,
                              size_t ws_size, hipStream_t stream) {
  const float* x = (const float*)d_in[0];
  const float* coef = (const float*)d_in[1];
  float* out = (float*)d_out;
  float* ws = (float*)d_ws;
  const int channels = out_size / 4096;  // 32*128 channels of 64x64
  init_tables<<<dim3(1), dim3(256), 0, stream>>>(ws);
  uppolyact_kernel<<<dim3(channels), dim3(256), 0, stream>>>(x, coef, ws, out);
}